// Round 15
// baseline (120.038 us; speedup 1.0000x reference)
//
#include <hip/hip_runtime.h>

#define HID 128
#define NBLK 64          // partition chunks
#define PTHREADS 1024    // threads per partition/hist block
#define MAXBUCK 2048     // buckets of 32 dst nodes; supports n <= 65536
#define CAP 3072         // LDS capacity (edges) per bucket in bucket_gather

typedef unsigned short ushort_t;
typedef unsigned int uint_t;
typedef short bf16x8 __attribute__((ext_vector_type(8)));
typedef float f32x4 __attribute__((ext_vector_type(4)));

__device__ __forceinline__ float bflo(uint_t u) { return __uint_as_float(u << 16); }
__device__ __forceinline__ float bfhi(uint_t u) { return __uint_as_float(u & 0xFFFF0000u); }
__device__ __forceinline__ uint_t f2bf(float f) {
    uint_t x = __float_as_uint(f);
    return (x + 0x7FFFu + ((x >> 16) & 1u)) >> 16;   // RNE
}

__device__ __forceinline__ int load_idx(const int* __restrict__ E, int pos, bool is64) {
    return is64 ? E[2 * pos] : E[pos];
}

// ---------------------------------------------------------------------------
// prep_hist (one launch, 1024 thr/block):
//   blocks 0..31  : transpose W1/W2 -> bf16 Wt[col][k]
//   block  32     : detect int64 vs int32 edge layout -> flag
//   blocks 33..33+NBLK-1 : per-block LDS histogram of dst buckets (both-valid)
// ---------------------------------------------------------------------------
__global__ __launch_bounds__(PTHREADS) void prep_hist(
    const int* __restrict__ E, int* __restrict__ flag,
    const float* __restrict__ W1, const float* __restrict__ W2,
    ushort_t* __restrict__ wt1, ushort_t* __restrict__ wt2,
    int* __restrict__ histT, int n_edges, int n_nodes, int nbuck)
{
    const int t = threadIdx.x;
    if (blockIdx.x < 32) {
        const int id = blockIdx.x * PTHREADS + t;        // 0..32767
        const float* W = (id < 16384) ? W1 : W2;
        ushort_t* O    = (id < 16384) ? wt1 : wt2;
        const int i   = id & 16383;
        const int col = i >> 7;
        const int k   = i & 127;
        O[col * 128 + k] = (ushort_t)f2bf(W[k * 128 + col]);
        return;
    }
    if (blockIdx.x == 32) {
        if (t < 64) {
            const int v = E[2 * t + 1] | E[2 * (t + 64) + 1];
            unsigned long long b = __ballot(v != 0);
            if (t == 0) flag[0] = (b == 0ull) ? 1 : 0;
        }
        return;
    }
    __shared__ int h[MAXBUCK];
    __shared__ int s_is64;
    const int hb = blockIdx.x - 33;
    if (t < 64) {
        const int v = E[2 * t + 1] | E[2 * (t + 64) + 1];
        unsigned long long b = __ballot(v != 0);
        if (t == 0) s_is64 = (b == 0ull) ? 1 : 0;
    }
    for (int i = t; i < nbuck; i += PTHREADS) h[i] = 0;
    __syncthreads();
    const bool is64 = (s_is64 != 0);
    const int chunk = (n_edges + NBLK - 1) / NBLK;
    const int c0 = hb * chunk;
    const int c1 = min(c0 + chunk, n_edges);
    for (int e = c0 + t; e < c1; e += PTHREADS) {
        const int src = load_idx(E, e, is64);
        const int dst = load_idx(E, n_edges + e, is64);
        if ((unsigned)src < (unsigned)n_nodes && (unsigned)dst < (unsigned)n_nodes)
            atomicAdd(&h[dst >> 5], 1);
    }
    __syncthreads();
    for (int i = t; i < nbuck; i += PTHREADS)
        histT[i * NBLK + hb] = h[i];
}

// ---------------------------------------------------------------------------
// MFMA GEMM (layer 1 + fallback): T = relu(X @ W + B).
// mode 0: write T rows (bf16). mode 1: fuse dot with Wf, write scalar S.
// ---------------------------------------------------------------------------
__global__ __launch_bounds__(256) void mlp_mfma(
    const float* __restrict__ X, const ushort_t* __restrict__ Wt,
    const float* __restrict__ Bv, const float* __restrict__ Wf,
    ushort_t* __restrict__ T, float* __restrict__ S, int n, int mode)
{
    __shared__ ushort_t Wl[HID * HID];   // 32 KB, swizzled

    {
        const uint4* src = (const uint4*)Wt;
        for (int o = threadIdx.x; o < 2048; o += 256) {
            const uint4 v = src[o];
            const int col = o >> 4;
            const int g   = o & 15;
            const int gs  = g ^ (col & 7);
            *(uint4*)(Wl + col * HID + gs * 8) = v;
        }
    }
    __syncthreads();

    const int l  = threadIdx.x & 63;
    const int wv = threadIdx.x >> 6;
    const int rowbase = blockIdx.x * 64 + wv * 16;
    const int lr = l & 15;
    const int lg = l >> 4;

    f32x4 acc[8];
#pragma unroll
    for (int ct = 0; ct < 8; ++ct) acc[ct] = (f32x4){0.f, 0.f, 0.f, 0.f};

    const int arow = rowbase + lr;
    const bool rok = (arow < n);

    for (int kk = 0; kk < 4; ++kk) {
        bf16x8 a;
        if (rok) {
            const float* xp = X + (size_t)arow * HID + kk * 32 + lg * 8;
            const float4 x0 = *(const float4*)xp;
            const float4 x1 = *(const float4*)(xp + 4);
            a[0] = (short)f2bf(x0.x); a[1] = (short)f2bf(x0.y);
            a[2] = (short)f2bf(x0.z); a[3] = (short)f2bf(x0.w);
            a[4] = (short)f2bf(x1.x); a[5] = (short)f2bf(x1.y);
            a[6] = (short)f2bf(x1.z); a[7] = (short)f2bf(x1.w);
        } else {
            a = (bf16x8){0, 0, 0, 0, 0, 0, 0, 0};
        }
#pragma unroll
        for (int ct = 0; ct < 8; ++ct) {
            const int col = ct * 16 + lr;
            const int g   = kk * 4 + lg;
            const int gs  = g ^ (col & 7);
            const bf16x8 b = *(const bf16x8*)(Wl + col * HID + gs * 8);
            acc[ct] = __builtin_amdgcn_mfma_f32_16x16x32_bf16(a, b, acc[ct], 0, 0, 0);
        }
    }

    if (mode == 0) {
#pragma unroll
        for (int ct = 0; ct < 8; ++ct) {
            const float bvc = Bv[ct * 16 + lr];
#pragma unroll
            for (int i = 0; i < 4; ++i) {
                const int r = rowbase + lg * 4 + i;
                if (r < n) {
                    const float v = fmaxf(acc[ct][i] + bvc, 0.f);
                    T[(size_t)r * HID + ct * 16 + lr] = (ushort_t)f2bf(v);
                }
            }
        }
    } else {
        float p0 = 0.f, p1 = 0.f, p2 = 0.f, p3 = 0.f;
#pragma unroll
        for (int ct = 0; ct < 8; ++ct) {
            const float bvc = Bv[ct * 16 + lr];
            const float wfc = Wf[ct * 16 + lr];
            p0 += fmaxf(acc[ct][0] + bvc, 0.f) * wfc;
            p1 += fmaxf(acc[ct][1] + bvc, 0.f) * wfc;
            p2 += fmaxf(acc[ct][2] + bvc, 0.f) * wfc;
            p3 += fmaxf(acc[ct][3] + bvc, 0.f) * wfc;
        }
#pragma unroll
        for (int m = 1; m <= 8; m <<= 1) {
            p0 += __shfl_xor(p0, m);
            p1 += __shfl_xor(p1, m);
            p2 += __shfl_xor(p2, m);
            p3 += __shfl_xor(p3, m);
        }
        if (lr == 0) {
            const int r = rowbase + lg * 4;
            if (r + 0 < n) S[r + 0] = p0;
            if (r + 1 < n) S[r + 1] = p1;
            if (r + 2 < n) S[r + 2] = p2;
            if (r + 3 < n) S[r + 3] = p3;
        }
    }
}

// ---------------------------------------------------------------------------
// scan_scatter: fused {self-service scan over histT} + {partition scatter}.
// Each of NBLK blocks reads all of histT (L2-resident, 400 KB), computes
// bucket totals + its own partial prefix, scans totals in LDS (<=2048 via
// 2 elems/thread), then scatters its edge chunk into per-(block,bucket)
// EXCLUSIVE ranges. Block 0 writes global bucketStart bs[0..nbuck].
// ---------------------------------------------------------------------------
__global__ __launch_bounds__(PTHREADS) void scan_scatter(
    const int* __restrict__ E, const int* __restrict__ flag,
    const int* __restrict__ histT, int* __restrict__ bs,
    uint_t* __restrict__ pe, int n_edges, int n_nodes, int nbuck)
{
    __shared__ int cur[MAXBUCK];   // partial prefix -> final positions
    __shared__ int tot[MAXBUCK];   // totals -> bucketStart (in-place)
    __shared__ int sd[PTHREADS];
    const int t = threadIdx.x;
    const int b = blockIdx.x;

    for (int i = t; i < nbuck; i += PTHREADS) {
        const int* row = histT + i * NBLK;
        int partial = 0, total = 0;
#pragma unroll 8
        for (int j = 0; j < NBLK; ++j) {
            const int v = row[j];
            total += v;
            if (j < b) partial += v;
        }
        cur[i] = partial;
        tot[i] = total;
    }
    __syncthreads();

    // exclusive scan of tot[0..nbuck) (2 elements per thread)
    const int i0 = 2 * t, i1 = 2 * t + 1;
    const int v0 = (i0 < nbuck) ? tot[i0] : 0;
    const int v1 = (i1 < nbuck) ? tot[i1] : 0;
    sd[t] = v0 + v1;
    __syncthreads();
    for (int d = 1; d < PTHREADS; d <<= 1) {
        const int u = (t >= d) ? sd[t - d] : 0;
        __syncthreads();
        sd[t] += u;
        __syncthreads();
    }
    const int pairExcl = sd[t] - (v0 + v1);
    if (i0 < nbuck) tot[i0] = pairExcl;
    if (i1 < nbuck) tot[i1] = pairExcl + v0;
    __syncthreads();

    for (int i = t; i < nbuck; i += PTHREADS) cur[i] += tot[i];
    if (b == 0) {
        for (int i = t; i < nbuck; i += PTHREADS) bs[i] = tot[i];
        if (t == PTHREADS - 1) bs[nbuck] = sd[PTHREADS - 1];   // grand total
    }
    __syncthreads();

    const bool is64 = (flag[0] != 0);
    const int chunk = (n_edges + NBLK - 1) / NBLK;
    const int c0 = b * chunk;
    const int c1 = min(c0 + chunk, n_edges);
    for (int e = c0 + t; e < c1; e += PTHREADS) {
        const int src = load_idx(E, e, is64);
        const int dst = load_idx(E, n_edges + e, is64);
        if ((unsigned)src >= (unsigned)n_nodes || (unsigned)dst >= (unsigned)n_nodes) continue;
        const int p = atomicAdd(&cur[dst >> 5], 1);
        pe[p] = (uint_t)src | ((uint_t)(dst & 31) << 16);
    }
}

// ---------------------------------------------------------------------------
// bucket_gather_mlp2: fused {bucket CSR build in LDS} + {vector gather of T}
// + {layer-2 MFMA GEMM + Wf-dot}. The 32x128 h-tile never touches global:
// gather accumulators -> swizzled bf16 LDS tile hA -> MFMA A-operand.
// Output: s[32 nodes] per bucket.
// ---------------------------------------------------------------------------
__global__ __launch_bounds__(256) void bucket_gather_mlp2(
    const uint_t* __restrict__ pe, const int* __restrict__ bs,
    const ushort_t* __restrict__ T, const ushort_t* __restrict__ Wt2,
    const float* __restrict__ b2, const float* __restrict__ Wf,
    float* __restrict__ S, int* __restrict__ ovf, int n_nodes, int nbuck)
{
    __shared__ ushort_t Wl[HID * HID];   // 32 KB, swizzled W2^T
    __shared__ ushort_t hA[32 * HID];    // 8 KB, swizzled bf16 h-tile
    __shared__ int sid[CAP];             // 12 KB
    __shared__ int cnt[32];
    __shared__ int cur[32];
    __shared__ int loff[32];
    const int b = blockIdx.x;
    const int t = threadIdx.x;
    const int start = bs[b];
    const int end   = bs[b + 1];
    const int m     = end - start;

    if (t < 32) cnt[t] = 0;
    // stage W2^T into LDS (overlaps with counting below via memory pipeline)
    {
        const uint4* src = (const uint4*)Wt2;
        for (int o = t; o < 2048; o += 256) {
            const uint4 v = src[o];
            const int col = o >> 4;
            const int g   = o & 15;
            const int gs  = g ^ (col & 7);
            *(uint4*)(Wl + col * HID + gs * 8) = v;
        }
    }
    __syncthreads();
    for (int i = start + t; i < end; i += 256)
        atomicAdd(&cnt[(pe[i] >> 16) & 31], 1);
    __syncthreads();
    if (t < 32) {
        const int v = cnt[t];
        int s = v;
        for (int d = 1; d < 32; d <<= 1) {
            const int u = __shfl_up(s, d, 64);
            if (t >= d) s += u;
        }
        const int excl = s - v;
        loff[t] = excl;
        cur[t]  = excl;
    }
    __syncthreads();

    const bool fits = (m <= CAP);
    for (int i = start + t; i < end; i += 256) {
        const uint_t w = pe[i];
        const int p = atomicAdd(&cur[(w >> 16) & 31], 1);
        const int s = (int)(w & 0xFFFFu);
        if (fits) sid[p] = s;
        else      ovf[start + p] = s;
    }
    __syncthreads();

    // gather T rows -> accumulate -> store swizzled bf16 into hA
    const int grp = t >> 5;
    const int l32 = t & 31;
    const int j0  = l32 * 4;
    for (int nd = grp; nd < 32; nd += 8) {
        const int node = b * 32 + nd;
        if (node >= n_nodes) break;
        const int k0 = loff[nd];
        const int k1 = (nd < 31) ? loff[nd + 1] : m;
        float4 a0 = {0.f, 0.f, 0.f, 0.f};
        float4 a1 = {0.f, 0.f, 0.f, 0.f};
        float4 a2 = {0.f, 0.f, 0.f, 0.f};
        float4 a3 = {0.f, 0.f, 0.f, 0.f};
        int k = k0;
        for (; k + 4 <= k1; k += 4) {
            const int s0 = fits ? sid[k + 0] : ovf[start + k + 0];
            const int s1 = fits ? sid[k + 1] : ovf[start + k + 1];
            const int s2 = fits ? sid[k + 2] : ovf[start + k + 2];
            const int s3 = fits ? sid[k + 3] : ovf[start + k + 3];
            const uint2 u0 = *(const uint2*)(T + (size_t)s0 * HID + j0);
            const uint2 u1 = *(const uint2*)(T + (size_t)s1 * HID + j0);
            const uint2 u2 = *(const uint2*)(T + (size_t)s2 * HID + j0);
            const uint2 u3 = *(const uint2*)(T + (size_t)s3 * HID + j0);
            a0.x += bflo(u0.x); a0.y += bfhi(u0.x);
            a0.z += bflo(u0.y); a0.w += bfhi(u0.y);
            a1.x += bflo(u1.x); a1.y += bfhi(u1.x);
            a1.z += bflo(u1.y); a1.w += bfhi(u1.y);
            a2.x += bflo(u2.x); a2.y += bfhi(u2.x);
            a2.z += bflo(u2.y); a2.w += bfhi(u2.y);
            a3.x += bflo(u3.x); a3.y += bfhi(u3.x);
            a3.z += bflo(u3.y); a3.w += bfhi(u3.y);
        }
        for (; k < k1; ++k) {
            const int s0 = fits ? sid[k] : ovf[start + k];
            const uint2 u0 = *(const uint2*)(T + (size_t)s0 * HID + j0);
            a0.x += bflo(u0.x); a0.y += bfhi(u0.x);
            a0.z += bflo(u0.y); a0.w += bfhi(u0.y);
        }
        a0.x += a1.x + a2.x + a3.x;
        a0.y += a1.y + a2.y + a3.y;
        a0.z += a1.z + a2.z + a3.z;
        a0.w += a1.w + a2.w + a3.w;
        // swizzled store: granule (l32>>1) ^ (nd&7), half (l32&1)
        uint2 w;
        w.x = f2bf(a0.x) | (f2bf(a0.y) << 16);
        w.y = f2bf(a0.z) | (f2bf(a0.w) << 16);
        char* dst = (char*)hA + nd * 256 + (((l32 >> 1) ^ (nd & 7)) << 4) + ((l32 & 1) << 3);
        *(uint2*)dst = w;
    }
    __syncthreads();

    // layer-2 GEMM on waves 0-1: rows wv*16+lr, A from hA, B from Wl
    const int wv = t >> 6;
    if (wv < 2) {
        const int l  = t & 63;
        const int lr = l & 15;
        const int lg = l >> 4;
        f32x4 acc[8];
#pragma unroll
        for (int ct = 0; ct < 8; ++ct) acc[ct] = (f32x4){0.f, 0.f, 0.f, 0.f};
        const int r = wv * 16 + lr;
#pragma unroll
        for (int kk = 0; kk < 4; ++kk) {
            const int g  = kk * 4 + lg;
            const bf16x8 a = *(const bf16x8*)((const char*)hA + r * 256 + ((g ^ (r & 7)) << 4));
#pragma unroll
            for (int ct = 0; ct < 8; ++ct) {
                const int col = ct * 16 + lr;
                const int gs  = g ^ (col & 7);
                const bf16x8 bb = *(const bf16x8*)(Wl + col * HID + gs * 8);
                acc[ct] = __builtin_amdgcn_mfma_f32_16x16x32_bf16(a, bb, acc[ct], 0, 0, 0);
            }
        }
        float p0 = 0.f, p1 = 0.f, p2 = 0.f, p3 = 0.f;
#pragma unroll
        for (int ct = 0; ct < 8; ++ct) {
            const float bvc = b2[ct * 16 + lr];
            const float wfc = Wf[ct * 16 + lr];
            p0 += fmaxf(acc[ct][0] + bvc, 0.f) * wfc;
            p1 += fmaxf(acc[ct][1] + bvc, 0.f) * wfc;
            p2 += fmaxf(acc[ct][2] + bvc, 0.f) * wfc;
            p3 += fmaxf(acc[ct][3] + bvc, 0.f) * wfc;
        }
#pragma unroll
        for (int mm = 1; mm <= 8; mm <<= 1) {
            p0 += __shfl_xor(p0, mm);
            p1 += __shfl_xor(p1, mm);
            p2 += __shfl_xor(p2, mm);
            p3 += __shfl_xor(p3, mm);
        }
        if (lr == 0) {
            const int rb = b * 32 + wv * 16 + lg * 4;
            if (rb + 0 < n_nodes) S[rb + 0] = p0;
            if (rb + 1 < n_nodes) S[rb + 1] = p1;
            if (rb + 2 < n_nodes) S[rb + 2] = p2;
            if (rb + 3 < n_nodes) S[rb + 3] = p3;
        }
    }
}

// ---------------------------------------------------------------------------
// Readout from pe directly: one block per bucket, 32 LDS float accumulators.
// ---------------------------------------------------------------------------
__global__ __launch_bounds__(256) void bucket_scalar(
    const uint_t* __restrict__ pe, const int* __restrict__ bs,
    const float* __restrict__ S, const float* __restrict__ bf,
    float* __restrict__ O, int n_nodes, int nbuck)
{
    __shared__ float acc[32];
    const int b = blockIdx.x;
    const int t = threadIdx.x;
    if (t < 32) acc[t] = 0.f;
    __syncthreads();
    const int start = bs[b];
    const int end   = bs[b + 1];
    for (int i = start + t; i < end; i += 256) {
        const uint_t w = pe[i];
        atomicAdd(&acc[(w >> 16) & 31], S[w & 0xFFFFu]);
    }
    __syncthreads();
    if (t < 32) {
        const int node = b * 32 + t;
        if (node < n_nodes) O[node] = bf[0] + acc[t];
    }
}

// ---------------------------------------------------------------------------
// Fallback atomic path (used only if workspace is too small for CSR)
// ---------------------------------------------------------------------------
__global__ __launch_bounds__(256) void scatter_vec(
    const ushort_t* __restrict__ T, const int* __restrict__ E,
    const int* __restrict__ flag, float* __restrict__ H,
    int n_edges, int n_nodes)
{
    const bool is64 = (flag[0] != 0);
    const int l32 = threadIdx.x & 31;
    const int j0  = l32 * 4;
    const int grp  = (int)((blockIdx.x * blockDim.x + threadIdx.x) >> 5);
    const int ngrp = (int)((gridDim.x * blockDim.x) >> 5);
    for (int e = grp; e < n_edges; e += ngrp) {
        const int src = load_idx(E, e, is64);
        const int dst = load_idx(E, n_edges + e, is64);
        if ((unsigned)src >= (unsigned)n_nodes || (unsigned)dst >= (unsigned)n_nodes) continue;
        const uint2 u = *(const uint2*)(T + (size_t)src * HID + j0);
        float* hp = H + (size_t)dst * HID + j0;
        unsafeAtomicAdd(hp + 0, bflo(u.x));
        unsafeAtomicAdd(hp + 1, bfhi(u.x));
        unsafeAtomicAdd(hp + 2, bflo(u.y));
        unsafeAtomicAdd(hp + 3, bfhi(u.y));
    }
}

__global__ __launch_bounds__(256) void scatter_scalar(
    const float* __restrict__ S, const int* __restrict__ E,
    const int* __restrict__ flag, float* __restrict__ O,
    int n_edges, int n_nodes)
{
    const bool is64 = (flag[0] != 0);
    const int t  = blockIdx.x * blockDim.x + threadIdx.x;
    const int nt = gridDim.x * blockDim.x;
    for (int e = t; e < n_edges; e += nt) {
        const int src = load_idx(E, e, is64);
        const int dst = load_idx(E, n_edges + e, is64);
        if ((unsigned)src >= (unsigned)n_nodes || (unsigned)dst >= (unsigned)n_nodes) continue;
        unsafeAtomicAdd(O + dst, S[src]);
    }
}

__global__ void init_out(float* __restrict__ O, const float* __restrict__ bf, int n) {
    int i = blockIdx.x * blockDim.x + threadIdx.x;
    if (i < n) O[i] = bf[0];
}

extern "C" void kernel_launch(void* const* d_in, const int* in_sizes, int n_in,
                              void* d_out, int out_size, void* d_ws, size_t ws_size,
                              hipStream_t stream) {
    const float* x  = (const float*)d_in[0];
    const int*   E  = (const int*)d_in[1];
    const float* W1 = (const float*)d_in[2];
    const float* b1 = (const float*)d_in[3];
    const float* W2 = (const float*)d_in[4];
    const float* b2 = (const float*)d_in[5];
    const float* Wf = (const float*)d_in[6];
    const float* bf = (const float*)d_in[7];
    float* out = (float*)d_out;

    const int n  = in_sizes[0] / HID;   // 50000 nodes
    const int ne = in_sizes[1] / 2;     // 800000 edges
    const int nbuck = (n + 31) / 32;    // 1563 buckets
    const int m     = nbuck * NBLK;     // 100,032 partition counters

    const size_t featB = (size_t)n * HID * 4;
    char* ws = (char*)d_ws;
    int*      flag = (int*)ws;
    ushort_t* wt1  = (ushort_t*)(ws + 1024);            // 32 KB
    ushort_t* wt2  = (ushort_t*)(ws + 1024 + 32768);    // 32 KB
    ushort_t* t1   = (ushort_t*)(ws + 1024 + 65536);    // n*128 bf16
    char*     p    = ws + 1024 + 65536 + featB / 2;
    float* s      = (float*)p;                  p += (size_t)n * 4;
    uint_t* pe    = (uint_t*)p;                 p += (size_t)ne * 4;
    int*   ovf    = (int*)p;                    p += (size_t)ne * 4;
    int*   histT  = (int*)p;                    p += (size_t)m * 4;
    int*   bs     = (int*)p;                    p += (size_t)(nbuck + 1) * 4;
    float* h1     = (float*)p;                  p += featB;     // fallback only
    const size_t needed = (size_t)(p - ws);

    const int gemm_grid = (n + 63) / 64;
    const bool csr_ok = (ws_size >= needed && n <= 65536 && nbuck <= MAXBUCK);

    // one launch: W transpose + is64 detect (+ dst histogram when CSR path)
    prep_hist<<<csr_ok ? (33 + NBLK) : 33, PTHREADS, 0, stream>>>(
        E, flag, W1, W2, wt1, wt2, histT, ne, n, nbuck);

    // layer 1 per-node transform (bf16 out) via MFMA
    mlp_mfma<<<gemm_grid, 256, 0, stream>>>(x, wt1, b1, nullptr, t1, nullptr, n, 0);

    if (csr_ok) {
        // fused scan + partition scatter (writes pe, bs)
        scan_scatter<<<NBLK, PTHREADS, 0, stream>>>(E, flag, histT, bs, pe, ne, n, nbuck);

        // fused bucket CSR + gather + layer-2 GEMM (writes s; h never global)
        bucket_gather_mlp2<<<nbuck, 256, 0, stream>>>(
            pe, bs, t1, wt2, b2, Wf, s, ovf, n, nbuck);

        // readout gather straight from pe
        bucket_scalar<<<nbuck, 256, 0, stream>>>(pe, bs, s, bf, out, n, nbuck);
    } else {
        // fallback: atomic scatter path
        (void)hipMemsetAsync(h1, 0, featB, stream);
        scatter_vec<<<8192, 256, 0, stream>>>(t1, E, flag, h1, ne, n);
        mlp_mfma<<<gemm_grid, 256, 0, stream>>>(h1, wt2, b2, Wf, nullptr, s, n, 1);
        init_out<<<(n + 255) / 256, 256, 0, stream>>>(out, bf, n);
        scatter_scalar<<<2048, 256, 0, stream>>>(s, E, flag, out, ne, n);
    }
}

// Round 16
// 98.144 us; speedup vs baseline: 1.2231x; 1.2231x over previous
//
#include <hip/hip_runtime.h>

#define HID 128
#define NBLK 64          // partition chunks
#define PTHREADS 1024    // threads per partition/hist block
#define MAXBUCK 2048     // buckets of 32 dst nodes; supports n <= 65536
#define CAP 3072         // LDS capacity (edges) per bucket in bucket_gather

typedef unsigned short ushort_t;
typedef unsigned int uint_t;
typedef short bf16x8 __attribute__((ext_vector_type(8)));
typedef float f32x4 __attribute__((ext_vector_type(4)));

__device__ __forceinline__ float bflo(uint_t u) { return __uint_as_float(u << 16); }
__device__ __forceinline__ float bfhi(uint_t u) { return __uint_as_float(u & 0xFFFF0000u); }
__device__ __forceinline__ uint_t f2bf(float f) {
    uint_t x = __float_as_uint(f);
    return (x + 0x7FFFu + ((x >> 16) & 1u)) >> 16;   // RNE
}

__device__ __forceinline__ int load_idx(const int* __restrict__ E, int pos, bool is64) {
    return is64 ? E[2 * pos] : E[pos];
}

// ---------------------------------------------------------------------------
// prep_hist (one launch, 1024 thr/block):
//   blocks 0..31  : transpose W1/W2 -> bf16 Wt[col][k]
//   block  32     : detect int64 vs int32 edge layout -> flag
//   blocks 33..33+NBLK-1 : per-block LDS histogram of dst buckets (both-valid)
// ---------------------------------------------------------------------------
__global__ __launch_bounds__(PTHREADS) void prep_hist(
    const int* __restrict__ E, int* __restrict__ flag,
    const float* __restrict__ W1, const float* __restrict__ W2,
    ushort_t* __restrict__ wt1, ushort_t* __restrict__ wt2,
    int* __restrict__ histT, int n_edges, int n_nodes, int nbuck)
{
    const int t = threadIdx.x;
    if (blockIdx.x < 32) {
        const int id = blockIdx.x * PTHREADS + t;        // 0..32767
        const float* W = (id < 16384) ? W1 : W2;
        ushort_t* O    = (id < 16384) ? wt1 : wt2;
        const int i   = id & 16383;
        const int col = i >> 7;
        const int k   = i & 127;
        O[col * 128 + k] = (ushort_t)f2bf(W[k * 128 + col]);
        return;
    }
    if (blockIdx.x == 32) {
        if (t < 64) {
            const int v = E[2 * t + 1] | E[2 * (t + 64) + 1];
            unsigned long long b = __ballot(v != 0);
            if (t == 0) flag[0] = (b == 0ull) ? 1 : 0;
        }
        return;
    }
    __shared__ int h[MAXBUCK];
    __shared__ int s_is64;
    const int hb = blockIdx.x - 33;
    if (t < 64) {
        const int v = E[2 * t + 1] | E[2 * (t + 64) + 1];
        unsigned long long b = __ballot(v != 0);
        if (t == 0) s_is64 = (b == 0ull) ? 1 : 0;
    }
    for (int i = t; i < nbuck; i += PTHREADS) h[i] = 0;
    __syncthreads();
    const bool is64 = (s_is64 != 0);
    const int chunk = (n_edges + NBLK - 1) / NBLK;
    const int c0 = hb * chunk;
    const int c1 = min(c0 + chunk, n_edges);
    for (int e = c0 + t; e < c1; e += PTHREADS) {
        const int src = load_idx(E, e, is64);
        const int dst = load_idx(E, n_edges + e, is64);
        if ((unsigned)src < (unsigned)n_nodes && (unsigned)dst < (unsigned)n_nodes)
            atomicAdd(&h[dst >> 5], 1);
    }
    __syncthreads();
    for (int i = t; i < nbuck; i += PTHREADS)
        histT[i * NBLK + hb] = h[i];
}

// ---------------------------------------------------------------------------
// MFMA GEMM: T = relu(X @ W + B) using v_mfma_f32_16x16x32_bf16.
// mode 0: write T rows (bf16). mode 1: fuse dot with Wf, write scalar S.
// ---------------------------------------------------------------------------
__global__ __launch_bounds__(256) void mlp_mfma(
    const float* __restrict__ X, const ushort_t* __restrict__ Wt,
    const float* __restrict__ Bv, const float* __restrict__ Wf,
    ushort_t* __restrict__ T, float* __restrict__ S, int n, int mode)
{
    __shared__ ushort_t Wl[HID * HID];   // 32 KB, swizzled

    {
        const uint4* src = (const uint4*)Wt;
        for (int o = threadIdx.x; o < 2048; o += 256) {
            const uint4 v = src[o];
            const int col = o >> 4;
            const int g   = o & 15;
            const int gs  = g ^ (col & 7);
            *(uint4*)(Wl + col * HID + gs * 8) = v;
        }
    }
    __syncthreads();

    const int l  = threadIdx.x & 63;
    const int wv = threadIdx.x >> 6;
    const int rowbase = blockIdx.x * 64 + wv * 16;
    const int lr = l & 15;
    const int lg = l >> 4;

    f32x4 acc[8];
#pragma unroll
    for (int ct = 0; ct < 8; ++ct) acc[ct] = (f32x4){0.f, 0.f, 0.f, 0.f};

    const int arow = rowbase + lr;
    const bool rok = (arow < n);

    for (int kk = 0; kk < 4; ++kk) {
        bf16x8 a;
        if (rok) {
            const float* xp = X + (size_t)arow * HID + kk * 32 + lg * 8;
            const float4 x0 = *(const float4*)xp;
            const float4 x1 = *(const float4*)(xp + 4);
            a[0] = (short)f2bf(x0.x); a[1] = (short)f2bf(x0.y);
            a[2] = (short)f2bf(x0.z); a[3] = (short)f2bf(x0.w);
            a[4] = (short)f2bf(x1.x); a[5] = (short)f2bf(x1.y);
            a[6] = (short)f2bf(x1.z); a[7] = (short)f2bf(x1.w);
        } else {
            a = (bf16x8){0, 0, 0, 0, 0, 0, 0, 0};
        }
#pragma unroll
        for (int ct = 0; ct < 8; ++ct) {
            const int col = ct * 16 + lr;
            const int g   = kk * 4 + lg;
            const int gs  = g ^ (col & 7);
            const bf16x8 b = *(const bf16x8*)(Wl + col * HID + gs * 8);
            acc[ct] = __builtin_amdgcn_mfma_f32_16x16x32_bf16(a, b, acc[ct], 0, 0, 0);
        }
    }

    if (mode == 0) {
#pragma unroll
        for (int ct = 0; ct < 8; ++ct) {
            const float bvc = Bv[ct * 16 + lr];
#pragma unroll
            for (int i = 0; i < 4; ++i) {
                const int r = rowbase + lg * 4 + i;
                if (r < n) {
                    const float v = fmaxf(acc[ct][i] + bvc, 0.f);
                    T[(size_t)r * HID + ct * 16 + lr] = (ushort_t)f2bf(v);
                }
            }
        }
    } else {
        float p0 = 0.f, p1 = 0.f, p2 = 0.f, p3 = 0.f;
#pragma unroll
        for (int ct = 0; ct < 8; ++ct) {
            const float bvc = Bv[ct * 16 + lr];
            const float wfc = Wf[ct * 16 + lr];
            p0 += fmaxf(acc[ct][0] + bvc, 0.f) * wfc;
            p1 += fmaxf(acc[ct][1] + bvc, 0.f) * wfc;
            p2 += fmaxf(acc[ct][2] + bvc, 0.f) * wfc;
            p3 += fmaxf(acc[ct][3] + bvc, 0.f) * wfc;
        }
#pragma unroll
        for (int m = 1; m <= 8; m <<= 1) {
            p0 += __shfl_xor(p0, m);
            p1 += __shfl_xor(p1, m);
            p2 += __shfl_xor(p2, m);
            p3 += __shfl_xor(p3, m);
        }
        if (lr == 0) {
            const int r = rowbase + lg * 4;
            if (r + 0 < n) S[r + 0] = p0;
            if (r + 1 < n) S[r + 1] = p1;
            if (r + 2 < n) S[r + 2] = p2;
            if (r + 3 < n) S[r + 3] = p3;
        }
    }
}

// ---------------------------------------------------------------------------
// Scan stage 1: per-256-chunk exclusive scan; block sums out.
// ---------------------------------------------------------------------------
__global__ __launch_bounds__(256) void scang_blk(
    const int* __restrict__ A, int* __restrict__ out,
    int* __restrict__ bsum, int m)
{
    __shared__ int sd[256];
    const int t = threadIdx.x;
    const int i = blockIdx.x * 256 + t;
    const int v = (i < m) ? A[i] : 0;
    sd[t] = v;
    __syncthreads();
    for (int d = 1; d < 256; d <<= 1) {
        const int u = (t >= d) ? sd[t - d] : 0;
        __syncthreads();
        sd[t] += u;
        __syncthreads();
    }
    if (i < m) out[i] = sd[t] - v;
    if (t == 255) bsum[blockIdx.x] = sd[255];
}

// ---------------------------------------------------------------------------
// Scan stage 2 (fused top-scan + add): block b sums bsum[0..b) locally and
// adds; block 0 also writes the grand total to out[m].
// ---------------------------------------------------------------------------
__global__ __launch_bounds__(256) void scang_add2(
    int* __restrict__ out, const int* __restrict__ bsum, int nb, int m)
{
    __shared__ int red[256];
    const int t = threadIdx.x;
    const int b = blockIdx.x;
    int partial = 0, total = 0;
    for (int i = t; i < nb; i += 256) {
        const int v = bsum[i];
        if (i < b) partial += v;
        total += v;
    }
    red[t] = partial;
    __syncthreads();
    for (int d = 128; d; d >>= 1) {
        if (t < d) red[t] += red[t + d];
        __syncthreads();
    }
    const int add = red[0];
    const int i = b * 256 + t;
    if (i < m) out[i] += add;
    if (b == 0) {
        __syncthreads();
        red[t] = total;
        __syncthreads();
        for (int d = 128; d; d >>= 1) {
            if (t < d) red[t] += red[t + d];
            __syncthreads();
        }
        if (t == 0) out[m] = red[0];
    }
}

// ---------------------------------------------------------------------------
// Partition scatter: packed (src | dlow<<16) into per-(block,bucket)
// EXCLUSIVE ranges; positions from LDS counters.
// ---------------------------------------------------------------------------
__global__ __launch_bounds__(PTHREADS) void part_scatter(
    const int* __restrict__ E, const int* __restrict__ flag,
    const int* __restrict__ basea, uint_t* __restrict__ pe,
    int n_edges, int n_nodes, int nbuck)
{
    __shared__ int cur[MAXBUCK];
    for (int i = threadIdx.x; i < nbuck; i += PTHREADS)
        cur[i] = basea[i * NBLK + blockIdx.x];
    __syncthreads();
    const bool is64 = (flag[0] != 0);
    const int chunk = (n_edges + NBLK - 1) / NBLK;
    const int c0 = blockIdx.x * chunk;
    const int c1 = min(c0 + chunk, n_edges);
    for (int e = c0 + (int)threadIdx.x; e < c1; e += PTHREADS) {
        const int src = load_idx(E, e, is64);
        const int dst = load_idx(E, n_edges + e, is64);
        if ((unsigned)src >= (unsigned)n_nodes || (unsigned)dst >= (unsigned)n_nodes) continue;
        const int p = atomicAdd(&cur[dst >> 5], 1);
        pe[p] = (uint_t)src | ((uint_t)(dst & 31) << 16);
    }
}

// ---------------------------------------------------------------------------
// Fused bucket CSR + vector gather: one 256-thread block per bucket of 32
// dst nodes. Per-dst sorted src list built in LDS; 8 x 32-lane groups gather
// T rows via LDS-resident indices. 8 independent loads in flight per iter
// (latency-bound phase -> maximize MLP).
// ---------------------------------------------------------------------------
__global__ __launch_bounds__(256) void bucket_gather(
    const uint_t* __restrict__ pe, const int* __restrict__ basea,
    const ushort_t* __restrict__ T, float* __restrict__ H,
    int* __restrict__ ovf, int n_nodes, int nbuck)
{
    __shared__ int sid[CAP];
    __shared__ int cnt[32];
    __shared__ int cur[32];
    __shared__ int loff[32];
    const int b = blockIdx.x;
    const int t = threadIdx.x;
    const int start = basea[b * NBLK];
    const int end   = basea[(b + 1) * NBLK];
    const int m     = end - start;

    if (t < 32) cnt[t] = 0;
    __syncthreads();
    for (int i = start + t; i < end; i += 256)
        atomicAdd(&cnt[(pe[i] >> 16) & 31], 1);
    __syncthreads();
    if (t < 32) {
        const int v = cnt[t];
        int s = v;
        for (int d = 1; d < 32; d <<= 1) {
            const int u = __shfl_up(s, d, 64);
            if (t >= d) s += u;
        }
        const int excl = s - v;
        loff[t] = excl;
        cur[t]  = excl;
    }
    __syncthreads();

    const bool fits = (m <= CAP);
    for (int i = start + t; i < end; i += 256) {
        const uint_t w = pe[i];
        const int p = atomicAdd(&cur[(w >> 16) & 31], 1);
        const int s = (int)(w & 0xFFFFu);
        if (fits) sid[p] = s;
        else      ovf[start + p] = s;
    }
    __syncthreads();

    const int grp = t >> 5;
    const int l32 = t & 31;
    const int j0  = l32 * 4;
    for (int nd = grp; nd < 32; nd += 8) {
        const int node = b * 32 + nd;
        if (node >= n_nodes) break;
        const int k0 = loff[nd];
        const int k1 = (nd < 31) ? loff[nd + 1] : m;
        float4 a0 = {0.f, 0.f, 0.f, 0.f};
        float4 a1 = {0.f, 0.f, 0.f, 0.f};
        float4 a2 = {0.f, 0.f, 0.f, 0.f};
        float4 a3 = {0.f, 0.f, 0.f, 0.f};
        int k = k0;
        // 8 loads in flight, 4 rotating accumulator chains
        for (; k + 8 <= k1; k += 8) {
            uint2 uu[8];
#pragma unroll
            for (int q = 0; q < 8; ++q) {
                const int s0 = fits ? sid[k + q] : ovf[start + k + q];
                uu[q] = *(const uint2*)(T + (size_t)s0 * HID + j0);
            }
#pragma unroll
            for (int q = 0; q < 8; q += 4) {
                a0.x += bflo(uu[q + 0].x); a0.y += bfhi(uu[q + 0].x);
                a0.z += bflo(uu[q + 0].y); a0.w += bfhi(uu[q + 0].y);
                a1.x += bflo(uu[q + 1].x); a1.y += bfhi(uu[q + 1].x);
                a1.z += bflo(uu[q + 1].y); a1.w += bfhi(uu[q + 1].y);
                a2.x += bflo(uu[q + 2].x); a2.y += bfhi(uu[q + 2].x);
                a2.z += bflo(uu[q + 2].y); a2.w += bfhi(uu[q + 2].y);
                a3.x += bflo(uu[q + 3].x); a3.y += bfhi(uu[q + 3].x);
                a3.z += bflo(uu[q + 3].y); a3.w += bfhi(uu[q + 3].y);
            }
        }
        for (; k + 4 <= k1; k += 4) {
            uint2 uu[4];
#pragma unroll
            for (int q = 0; q < 4; ++q) {
                const int s0 = fits ? sid[k + q] : ovf[start + k + q];
                uu[q] = *(const uint2*)(T + (size_t)s0 * HID + j0);
            }
            a0.x += bflo(uu[0].x); a0.y += bfhi(uu[0].x);
            a0.z += bflo(uu[0].y); a0.w += bfhi(uu[0].y);
            a1.x += bflo(uu[1].x); a1.y += bfhi(uu[1].x);
            a1.z += bflo(uu[1].y); a1.w += bfhi(uu[1].y);
            a2.x += bflo(uu[2].x); a2.y += bfhi(uu[2].x);
            a2.z += bflo(uu[2].y); a2.w += bfhi(uu[2].y);
            a3.x += bflo(uu[3].x); a3.y += bfhi(uu[3].x);
            a3.z += bflo(uu[3].y); a3.w += bfhi(uu[3].y);
        }
        for (; k < k1; ++k) {
            const int s0 = fits ? sid[k] : ovf[start + k];
            const uint2 u0 = *(const uint2*)(T + (size_t)s0 * HID + j0);
            a0.x += bflo(u0.x); a0.y += bfhi(u0.x);
            a0.z += bflo(u0.y); a0.w += bfhi(u0.y);
        }
        a0.x += a1.x + a2.x + a3.x;
        a0.y += a1.y + a2.y + a3.y;
        a0.z += a1.z + a2.z + a3.z;
        a0.w += a1.w + a2.w + a3.w;
        *(float4*)(H + (size_t)node * HID + j0) = a0;
    }
}

// ---------------------------------------------------------------------------
// Readout from pe directly: one block per bucket, 32 LDS float accumulators.
// ---------------------------------------------------------------------------
__global__ __launch_bounds__(256) void bucket_scalar(
    const uint_t* __restrict__ pe, const int* __restrict__ basea,
    const float* __restrict__ S, const float* __restrict__ bf,
    float* __restrict__ O, int n_nodes, int nbuck)
{
    __shared__ float acc[32];
    const int b = blockIdx.x;
    const int t = threadIdx.x;
    if (t < 32) acc[t] = 0.f;
    __syncthreads();
    const int start = basea[b * NBLK];
    const int end   = basea[(b + 1) * NBLK];
    for (int i = start + t; i < end; i += 256) {
        const uint_t w = pe[i];
        atomicAdd(&acc[(w >> 16) & 31], S[w & 0xFFFFu]);
    }
    __syncthreads();
    if (t < 32) {
        const int node = b * 32 + t;
        if (node < n_nodes) O[node] = bf[0] + acc[t];
    }
}

// ---------------------------------------------------------------------------
// Fallback atomic path (used only if workspace is too small for CSR)
// ---------------------------------------------------------------------------
__global__ __launch_bounds__(256) void scatter_vec(
    const ushort_t* __restrict__ T, const int* __restrict__ E,
    const int* __restrict__ flag, float* __restrict__ H,
    int n_edges, int n_nodes)
{
    const bool is64 = (flag[0] != 0);
    const int l32 = threadIdx.x & 31;
    const int j0  = l32 * 4;
    const int grp  = (int)((blockIdx.x * blockDim.x + threadIdx.x) >> 5);
    const int ngrp = (int)((gridDim.x * blockDim.x) >> 5);
    for (int e = grp; e < n_edges; e += ngrp) {
        const int src = load_idx(E, e, is64);
        const int dst = load_idx(E, n_edges + e, is64);
        if ((unsigned)src >= (unsigned)n_nodes || (unsigned)dst >= (unsigned)n_nodes) continue;
        const uint2 u = *(const uint2*)(T + (size_t)src * HID + j0);
        float* hp = H + (size_t)dst * HID + j0;
        unsafeAtomicAdd(hp + 0, bflo(u.x));
        unsafeAtomicAdd(hp + 1, bfhi(u.x));
        unsafeAtomicAdd(hp + 2, bflo(u.y));
        unsafeAtomicAdd(hp + 3, bfhi(u.y));
    }
}

__global__ __launch_bounds__(256) void scatter_scalar(
    const float* __restrict__ S, const int* __restrict__ E,
    const int* __restrict__ flag, float* __restrict__ O,
    int n_edges, int n_nodes)
{
    const bool is64 = (flag[0] != 0);
    const int t  = blockIdx.x * blockDim.x + threadIdx.x;
    const int nt = gridDim.x * blockDim.x;
    for (int e = t; e < n_edges; e += nt) {
        const int src = load_idx(E, e, is64);
        const int dst = load_idx(E, n_edges + e, is64);
        if ((unsigned)src >= (unsigned)n_nodes || (unsigned)dst >= (unsigned)n_nodes) continue;
        unsafeAtomicAdd(O + dst, S[src]);
    }
}

__global__ void init_out(float* __restrict__ O, const float* __restrict__ bf, int n) {
    int i = blockIdx.x * blockDim.x + threadIdx.x;
    if (i < n) O[i] = bf[0];
}

extern "C" void kernel_launch(void* const* d_in, const int* in_sizes, int n_in,
                              void* d_out, int out_size, void* d_ws, size_t ws_size,
                              hipStream_t stream) {
    const float* x  = (const float*)d_in[0];
    const int*   E  = (const int*)d_in[1];
    const float* W1 = (const float*)d_in[2];
    const float* b1 = (const float*)d_in[3];
    const float* W2 = (const float*)d_in[4];
    const float* b2 = (const float*)d_in[5];
    const float* Wf = (const float*)d_in[6];
    const float* bf = (const float*)d_in[7];
    float* out = (float*)d_out;

    const int n  = in_sizes[0] / HID;   // 50000 nodes
    const int ne = in_sizes[1] / 2;     // 800000 edges
    const int nbuck  = (n + 31) / 32;   // 1563 buckets
    const int m      = nbuck * NBLK;    // 100,032 partition counters
    const int nbscan = (m + 255) / 256; // 391 scan blocks

    const size_t featB = (size_t)n * HID * 4;
    char* ws = (char*)d_ws;
    int*      flag = (int*)ws;
    ushort_t* wt1  = (ushort_t*)(ws + 1024);            // 32 KB
    ushort_t* wt2  = (ushort_t*)(ws + 1024 + 32768);    // 32 KB
    ushort_t* t1   = (ushort_t*)(ws + 1024 + 65536);    // n*128 bf16 (in featB slot)
    float*    h1   = (float*)(ws + 1024 + 65536 + featB);
    char*     p    = ws + 1024 + 65536 + 2 * featB;
    uint_t* pe    = (uint_t*)p;                 p += (size_t)ne * 4;
    int*   ovf    = (int*)p;                    p += (size_t)ne * 4;
    int*   histT  = (int*)p;                    p += (size_t)m * 4;
    int*   basea  = (int*)p;                    p += (size_t)(m + 1) * 4;
    int*   bsum   = (int*)p;                    p += (size_t)nbscan * 4;
    const size_t needed = (size_t)(p - ws);
    float* s = (float*)(ws + 1024 + 65536);   // t1 dead after aggregation; reuse slot

    const int gemm_grid = (n + 63) / 64;
    const bool csr_ok = (ws_size >= needed && n <= 65536 && nbuck <= MAXBUCK);

    // one launch: W transpose + is64 detect (+ dst histogram when CSR path)
    prep_hist<<<csr_ok ? (33 + NBLK) : 33, PTHREADS, 0, stream>>>(
        E, flag, W1, W2, wt1, wt2, histT, ne, n, nbuck);

    // layer 1 per-node transform (bf16 out) via MFMA
    mlp_mfma<<<gemm_grid, 256, 0, stream>>>(x, wt1, b1, nullptr, t1, nullptr, n, 0);

    if (csr_ok) {
        scang_blk<<<nbscan, 256, 0, stream>>>(histT, basea, bsum, m);
        scang_add2<<<nbscan, 256, 0, stream>>>(basea, bsum, nbscan, m);
        part_scatter<<<NBLK, PTHREADS, 0, stream>>>(E, flag, basea, pe, ne, n, nbuck);

        // fused bucket CSR + vector gather (writes H)
        bucket_gather<<<nbuck, 256, 0, stream>>>(pe, basea, t1, h1, ovf, n, nbuck);

        // layer 2 fused with readout: s[m] = relu(h1[m]@W2+b2) . Wf
        mlp_mfma<<<gemm_grid, 256, 0, stream>>>(h1, wt2, b2, Wf, nullptr, s, n, 1);

        // readout gather straight from pe
        bucket_scalar<<<nbuck, 256, 0, stream>>>(pe, basea, s, bf, out, n, nbuck);
    } else {
        // fallback: atomic scatter path
        (void)hipMemsetAsync(h1, 0, featB, stream);
        scatter_vec<<<8192, 256, 0, stream>>>(t1, E, flag, h1, ne, n);
        mlp_mfma<<<gemm_grid, 256, 0, stream>>>(h1, wt2, b2, Wf, nullptr, s, n, 1);
        init_out<<<(n + 255) / 256, 256, 0, stream>>>(out, bf, n);
        scatter_scalar<<<2048, 256, 0, stream>>>(s, E, flag, out, ne, n);
    }
}

// Round 17
// 92.066 us; speedup vs baseline: 1.3038x; 1.0660x over previous
//
#include <hip/hip_runtime.h>

#define HID 128
#define NBLK 128         // partition chunks
#define PTHREADS 1024    // threads per partition/hist block
#define MAXBUCK 2048     // buckets of 32 dst nodes; supports n <= 65536
#define CAP 3072         // LDS capacity (edges) per bucket in bucket_gather

typedef unsigned short ushort_t;
typedef unsigned int uint_t;
typedef short bf16x8 __attribute__((ext_vector_type(8)));
typedef float f32x4 __attribute__((ext_vector_type(4)));

__device__ __forceinline__ float bflo(uint_t u) { return __uint_as_float(u << 16); }
__device__ __forceinline__ float bfhi(uint_t u) { return __uint_as_float(u & 0xFFFF0000u); }
__device__ __forceinline__ uint_t f2bf(float f) {
    uint_t x = __float_as_uint(f);
    return (x + 0x7FFFu + ((x >> 16) & 1u)) >> 16;   // RNE
}

__device__ __forceinline__ int load_idx(const int* __restrict__ E, int pos, bool is64) {
    return is64 ? E[2 * pos] : E[pos];
}

// ---------------------------------------------------------------------------
// prep_hist (one launch, 1024 thr/block):
//   blocks 0..31  : transpose W1/W2 -> bf16 Wt[col][k]
//   block  32     : detect int64 vs int32 edge layout -> flag
//   blocks 33..33+NBLK-1 : per-block LDS histogram of dst buckets (both-valid)
// ---------------------------------------------------------------------------
__global__ __launch_bounds__(PTHREADS) void prep_hist(
    const int* __restrict__ E, int* __restrict__ flag,
    const float* __restrict__ W1, const float* __restrict__ W2,
    ushort_t* __restrict__ wt1, ushort_t* __restrict__ wt2,
    int* __restrict__ histT, int n_edges, int n_nodes, int nbuck)
{
    const int t = threadIdx.x;
    if (blockIdx.x < 32) {
        const int id = blockIdx.x * PTHREADS + t;        // 0..32767
        const float* W = (id < 16384) ? W1 : W2;
        ushort_t* O    = (id < 16384) ? wt1 : wt2;
        const int i   = id & 16383;
        const int col = i >> 7;
        const int k   = i & 127;
        O[col * 128 + k] = (ushort_t)f2bf(W[k * 128 + col]);
        return;
    }
    if (blockIdx.x == 32) {
        if (t < 64) {
            const int v = E[2 * t + 1] | E[2 * (t + 64) + 1];
            unsigned long long b = __ballot(v != 0);
            if (t == 0) flag[0] = (b == 0ull) ? 1 : 0;
        }
        return;
    }
    __shared__ int h[MAXBUCK];
    __shared__ int s_is64;
    const int hb = blockIdx.x - 33;
    if (t < 64) {
        const int v = E[2 * t + 1] | E[2 * (t + 64) + 1];
        unsigned long long b = __ballot(v != 0);
        if (t == 0) s_is64 = (b == 0ull) ? 1 : 0;
    }
    for (int i = t; i < nbuck; i += PTHREADS) h[i] = 0;
    __syncthreads();
    const bool is64 = (s_is64 != 0);
    const int chunk = (n_edges + NBLK - 1) / NBLK;
    const int c0 = hb * chunk;
    const int c1 = min(c0 + chunk, n_edges);
    for (int e = c0 + t; e < c1; e += PTHREADS) {
        const int src = load_idx(E, e, is64);
        const int dst = load_idx(E, n_edges + e, is64);
        if ((unsigned)src < (unsigned)n_nodes && (unsigned)dst < (unsigned)n_nodes)
            atomicAdd(&h[dst >> 5], 1);
    }
    __syncthreads();
    for (int i = t; i < nbuck; i += PTHREADS)
        histT[i * NBLK + hb] = h[i];
}

// ---------------------------------------------------------------------------
// MFMA GEMM: T = relu(X @ W + B) using v_mfma_f32_16x16x32_bf16.
// mode 0: write T rows (bf16). mode 1: fuse dot with Wf, write scalar S.
// ---------------------------------------------------------------------------
__global__ __launch_bounds__(256) void mlp_mfma(
    const float* __restrict__ X, const ushort_t* __restrict__ Wt,
    const float* __restrict__ Bv, const float* __restrict__ Wf,
    ushort_t* __restrict__ T, float* __restrict__ S, int n, int mode)
{
    __shared__ ushort_t Wl[HID * HID];   // 32 KB, swizzled

    {
        const uint4* src = (const uint4*)Wt;
        for (int o = threadIdx.x; o < 2048; o += 256) {
            const uint4 v = src[o];
            const int col = o >> 4;
            const int g   = o & 15;
            const int gs  = g ^ (col & 7);
            *(uint4*)(Wl + col * HID + gs * 8) = v;
        }
    }
    __syncthreads();

    const int l  = threadIdx.x & 63;
    const int wv = threadIdx.x >> 6;
    const int rowbase = blockIdx.x * 64 + wv * 16;
    const int lr = l & 15;
    const int lg = l >> 4;

    f32x4 acc[8];
#pragma unroll
    for (int ct = 0; ct < 8; ++ct) acc[ct] = (f32x4){0.f, 0.f, 0.f, 0.f};

    const int arow = rowbase + lr;
    const bool rok = (arow < n);

    for (int kk = 0; kk < 4; ++kk) {
        bf16x8 a;
        if (rok) {
            const float* xp = X + (size_t)arow * HID + kk * 32 + lg * 8;
            const float4 x0 = *(const float4*)xp;
            const float4 x1 = *(const float4*)(xp + 4);
            a[0] = (short)f2bf(x0.x); a[1] = (short)f2bf(x0.y);
            a[2] = (short)f2bf(x0.z); a[3] = (short)f2bf(x0.w);
            a[4] = (short)f2bf(x1.x); a[5] = (short)f2bf(x1.y);
            a[6] = (short)f2bf(x1.z); a[7] = (short)f2bf(x1.w);
        } else {
            a = (bf16x8){0, 0, 0, 0, 0, 0, 0, 0};
        }
#pragma unroll
        for (int ct = 0; ct < 8; ++ct) {
            const int col = ct * 16 + lr;
            const int g   = kk * 4 + lg;
            const int gs  = g ^ (col & 7);
            const bf16x8 b = *(const bf16x8*)(Wl + col * HID + gs * 8);
            acc[ct] = __builtin_amdgcn_mfma_f32_16x16x32_bf16(a, b, acc[ct], 0, 0, 0);
        }
    }

    if (mode == 0) {
#pragma unroll
        for (int ct = 0; ct < 8; ++ct) {
            const float bvc = Bv[ct * 16 + lr];
#pragma unroll
            for (int i = 0; i < 4; ++i) {
                const int r = rowbase + lg * 4 + i;
                if (r < n) {
                    const float v = fmaxf(acc[ct][i] + bvc, 0.f);
                    T[(size_t)r * HID + ct * 16 + lr] = (ushort_t)f2bf(v);
                }
            }
        }
    } else {
        float p0 = 0.f, p1 = 0.f, p2 = 0.f, p3 = 0.f;
#pragma unroll
        for (int ct = 0; ct < 8; ++ct) {
            const float bvc = Bv[ct * 16 + lr];
            const float wfc = Wf[ct * 16 + lr];
            p0 += fmaxf(acc[ct][0] + bvc, 0.f) * wfc;
            p1 += fmaxf(acc[ct][1] + bvc, 0.f) * wfc;
            p2 += fmaxf(acc[ct][2] + bvc, 0.f) * wfc;
            p3 += fmaxf(acc[ct][3] + bvc, 0.f) * wfc;
        }
#pragma unroll
        for (int m = 1; m <= 8; m <<= 1) {
            p0 += __shfl_xor(p0, m);
            p1 += __shfl_xor(p1, m);
            p2 += __shfl_xor(p2, m);
            p3 += __shfl_xor(p3, m);
        }
        if (lr == 0) {
            const int r = rowbase + lg * 4;
            if (r + 0 < n) S[r + 0] = p0;
            if (r + 1 < n) S[r + 1] = p1;
            if (r + 2 < n) S[r + 2] = p2;
            if (r + 3 < n) S[r + 3] = p3;
        }
    }
}

// ---------------------------------------------------------------------------
// Scan stage 1: per-256-chunk exclusive scan; block sums out.
// ---------------------------------------------------------------------------
__global__ __launch_bounds__(256) void scang_blk(
    const int* __restrict__ A, int* __restrict__ out,
    int* __restrict__ bsum, int m)
{
    __shared__ int sd[256];
    const int t = threadIdx.x;
    const int i = blockIdx.x * 256 + t;
    const int v = (i < m) ? A[i] : 0;
    sd[t] = v;
    __syncthreads();
    for (int d = 1; d < 256; d <<= 1) {
        const int u = (t >= d) ? sd[t - d] : 0;
        __syncthreads();
        sd[t] += u;
        __syncthreads();
    }
    if (i < m) out[i] = sd[t] - v;
    if (t == 255) bsum[blockIdx.x] = sd[255];
}

// ---------------------------------------------------------------------------
// Scan stage 2 (fused top-scan + add): block b sums bsum[0..b) locally and
// adds; block 0 also writes the grand total to out[m].
// ---------------------------------------------------------------------------
__global__ __launch_bounds__(256) void scang_add2(
    int* __restrict__ out, const int* __restrict__ bsum, int nb, int m)
{
    __shared__ int red[256];
    const int t = threadIdx.x;
    const int b = blockIdx.x;
    int partial = 0, total = 0;
    for (int i = t; i < nb; i += 256) {
        const int v = bsum[i];
        if (i < b) partial += v;
        total += v;
    }
    red[t] = partial;
    __syncthreads();
    for (int d = 128; d; d >>= 1) {
        if (t < d) red[t] += red[t + d];
        __syncthreads();
    }
    const int add = red[0];
    const int i = b * 256 + t;
    if (i < m) out[i] += add;
    if (b == 0) {
        __syncthreads();
        red[t] = total;
        __syncthreads();
        for (int d = 128; d; d >>= 1) {
            if (t < d) red[t] += red[t + d];
            __syncthreads();
        }
        if (t == 0) out[m] = red[0];
    }
}

// ---------------------------------------------------------------------------
// Partition scatter: packed (src | dlow<<16) into per-(block,bucket)
// EXCLUSIVE ranges; positions from LDS counters.
// ---------------------------------------------------------------------------
__global__ __launch_bounds__(PTHREADS) void part_scatter(
    const int* __restrict__ E, const int* __restrict__ flag,
    const int* __restrict__ basea, uint_t* __restrict__ pe,
    int n_edges, int n_nodes, int nbuck)
{
    __shared__ int cur[MAXBUCK];
    for (int i = threadIdx.x; i < nbuck; i += PTHREADS)
        cur[i] = basea[i * NBLK + blockIdx.x];
    __syncthreads();
    const bool is64 = (flag[0] != 0);
    const int chunk = (n_edges + NBLK - 1) / NBLK;
    const int c0 = blockIdx.x * chunk;
    const int c1 = min(c0 + chunk, n_edges);
    for (int e = c0 + (int)threadIdx.x; e < c1; e += PTHREADS) {
        const int src = load_idx(E, e, is64);
        const int dst = load_idx(E, n_edges + e, is64);
        if ((unsigned)src >= (unsigned)n_nodes || (unsigned)dst >= (unsigned)n_nodes) continue;
        const int p = atomicAdd(&cur[dst >> 5], 1);
        pe[p] = (uint_t)src | ((uint_t)(dst & 31) << 16);
    }
}

// ---------------------------------------------------------------------------
// Fused bucket CSR + vector gather: one 256-thread block per bucket of 32
// dst nodes. Per-dst sorted src list built in LDS; 8 x 32-lane groups gather
// T rows via LDS-resident indices. 8 independent loads in flight per iter.
// ---------------------------------------------------------------------------
__global__ __launch_bounds__(256) void bucket_gather(
    const uint_t* __restrict__ pe, const int* __restrict__ basea,
    const ushort_t* __restrict__ T, float* __restrict__ H,
    int* __restrict__ ovf, int n_nodes, int nbuck)
{
    __shared__ int sid[CAP];
    __shared__ int cnt[32];
    __shared__ int cur[32];
    __shared__ int loff[32];
    const int b = blockIdx.x;
    const int t = threadIdx.x;
    const int start = basea[b * NBLK];
    const int end   = basea[(b + 1) * NBLK];
    const int m     = end - start;

    if (t < 32) cnt[t] = 0;
    __syncthreads();
    for (int i = start + t; i < end; i += 256)
        atomicAdd(&cnt[(pe[i] >> 16) & 31], 1);
    __syncthreads();
    if (t < 32) {
        const int v = cnt[t];
        int s = v;
        for (int d = 1; d < 32; d <<= 1) {
            const int u = __shfl_up(s, d, 64);
            if (t >= d) s += u;
        }
        const int excl = s - v;
        loff[t] = excl;
        cur[t]  = excl;
    }
    __syncthreads();

    const bool fits = (m <= CAP);
    for (int i = start + t; i < end; i += 256) {
        const uint_t w = pe[i];
        const int p = atomicAdd(&cur[(w >> 16) & 31], 1);
        const int s = (int)(w & 0xFFFFu);
        if (fits) sid[p] = s;
        else      ovf[start + p] = s;
    }
    __syncthreads();

    const int grp = t >> 5;
    const int l32 = t & 31;
    const int j0  = l32 * 4;
    for (int nd = grp; nd < 32; nd += 8) {
        const int node = b * 32 + nd;
        if (node >= n_nodes) break;
        const int k0 = loff[nd];
        const int k1 = (nd < 31) ? loff[nd + 1] : m;
        float4 a0 = {0.f, 0.f, 0.f, 0.f};
        float4 a1 = {0.f, 0.f, 0.f, 0.f};
        float4 a2 = {0.f, 0.f, 0.f, 0.f};
        float4 a3 = {0.f, 0.f, 0.f, 0.f};
        int k = k0;
        for (; k + 8 <= k1; k += 8) {
            uint2 uu[8];
#pragma unroll
            for (int q = 0; q < 8; ++q) {
                const int s0 = fits ? sid[k + q] : ovf[start + k + q];
                uu[q] = *(const uint2*)(T + (size_t)s0 * HID + j0);
            }
#pragma unroll
            for (int q = 0; q < 8; q += 4) {
                a0.x += bflo(uu[q + 0].x); a0.y += bfhi(uu[q + 0].x);
                a0.z += bflo(uu[q + 0].y); a0.w += bfhi(uu[q + 0].y);
                a1.x += bflo(uu[q + 1].x); a1.y += bfhi(uu[q + 1].x);
                a1.z += bflo(uu[q + 1].y); a1.w += bfhi(uu[q + 1].y);
                a2.x += bflo(uu[q + 2].x); a2.y += bfhi(uu[q + 2].x);
                a2.z += bflo(uu[q + 2].y); a2.w += bfhi(uu[q + 2].y);
                a3.x += bflo(uu[q + 3].x); a3.y += bfhi(uu[q + 3].x);
                a3.z += bflo(uu[q + 3].y); a3.w += bfhi(uu[q + 3].y);
            }
        }
        for (; k + 4 <= k1; k += 4) {
            uint2 uu[4];
#pragma unroll
            for (int q = 0; q < 4; ++q) {
                const int s0 = fits ? sid[k + q] : ovf[start + k + q];
                uu[q] = *(const uint2*)(T + (size_t)s0 * HID + j0);
            }
            a0.x += bflo(uu[0].x); a0.y += bfhi(uu[0].x);
            a0.z += bflo(uu[0].y); a0.w += bfhi(uu[0].y);
            a1.x += bflo(uu[1].x); a1.y += bfhi(uu[1].x);
            a1.z += bflo(uu[1].y); a1.w += bfhi(uu[1].y);
            a2.x += bflo(uu[2].x); a2.y += bfhi(uu[2].x);
            a2.z += bflo(uu[2].y); a2.w += bfhi(uu[2].y);
            a3.x += bflo(uu[3].x); a3.y += bfhi(uu[3].x);
            a3.z += bflo(uu[3].y); a3.w += bfhi(uu[3].y);
        }
        for (; k < k1; ++k) {
            const int s0 = fits ? sid[k] : ovf[start + k];
            const uint2 u0 = *(const uint2*)(T + (size_t)s0 * HID + j0);
            a0.x += bflo(u0.x); a0.y += bfhi(u0.x);
            a0.z += bflo(u0.y); a0.w += bfhi(u0.y);
        }
        a0.x += a1.x + a2.x + a3.x;
        a0.y += a1.y + a2.y + a3.y;
        a0.z += a1.z + a2.z + a3.z;
        a0.w += a1.w + a2.w + a3.w;
        *(float4*)(H + (size_t)node * HID + j0) = a0;
    }
}

// ---------------------------------------------------------------------------
// Readout from pe directly: one block per bucket, 32 LDS float accumulators.
// ---------------------------------------------------------------------------
__global__ __launch_bounds__(256) void bucket_scalar(
    const uint_t* __restrict__ pe, const int* __restrict__ basea,
    const float* __restrict__ S, const float* __restrict__ bf,
    float* __restrict__ O, int n_nodes, int nbuck)
{
    __shared__ float acc[32];
    const int b = blockIdx.x;
    const int t = threadIdx.x;
    if (t < 32) acc[t] = 0.f;
    __syncthreads();
    const int start = basea[b * NBLK];
    const int end   = basea[(b + 1) * NBLK];
    for (int i = start + t; i < end; i += 256) {
        const uint_t w = pe[i];
        atomicAdd(&acc[(w >> 16) & 31], S[w & 0xFFFFu]);
    }
    __syncthreads();
    if (t < 32) {
        const int node = b * 32 + t;
        if (node < n_nodes) O[node] = bf[0] + acc[t];
    }
}

// ---------------------------------------------------------------------------
// Fallback atomic path (used only if workspace is too small for CSR)
// ---------------------------------------------------------------------------
__global__ __launch_bounds__(256) void scatter_vec(
    const ushort_t* __restrict__ T, const int* __restrict__ E,
    const int* __restrict__ flag, float* __restrict__ H,
    int n_edges, int n_nodes)
{
    const bool is64 = (flag[0] != 0);
    const int l32 = threadIdx.x & 31;
    const int j0  = l32 * 4;
    const int grp  = (int)((blockIdx.x * blockDim.x + threadIdx.x) >> 5);
    const int ngrp = (int)((gridDim.x * blockDim.x) >> 5);
    for (int e = grp; e < n_edges; e += ngrp) {
        const int src = load_idx(E, e, is64);
        const int dst = load_idx(E, n_edges + e, is64);
        if ((unsigned)src >= (unsigned)n_nodes || (unsigned)dst >= (unsigned)n_nodes) continue;
        const uint2 u = *(const uint2*)(T + (size_t)src * HID + j0);
        float* hp = H + (size_t)dst * HID + j0;
        unsafeAtomicAdd(hp + 0, bflo(u.x));
        unsafeAtomicAdd(hp + 1, bfhi(u.x));
        unsafeAtomicAdd(hp + 2, bflo(u.y));
        unsafeAtomicAdd(hp + 3, bfhi(u.y));
    }
}

__global__ __launch_bounds__(256) void scatter_scalar(
    const float* __restrict__ S, const int* __restrict__ E,
    const int* __restrict__ flag, float* __restrict__ O,
    int n_edges, int n_nodes)
{
    const bool is64 = (flag[0] != 0);
    const int t  = blockIdx.x * blockDim.x + threadIdx.x;
    const int nt = gridDim.x * blockDim.x;
    for (int e = t; e < n_edges; e += nt) {
        const int src = load_idx(E, e, is64);
        const int dst = load_idx(E, n_edges + e, is64);
        if ((unsigned)src >= (unsigned)n_nodes || (unsigned)dst >= (unsigned)n_nodes) continue;
        unsafeAtomicAdd(O + dst, S[src]);
    }
}

__global__ void init_out(float* __restrict__ O, const float* __restrict__ bf, int n) {
    int i = blockIdx.x * blockDim.x + threadIdx.x;
    if (i < n) O[i] = bf[0];
}

extern "C" void kernel_launch(void* const* d_in, const int* in_sizes, int n_in,
                              void* d_out, int out_size, void* d_ws, size_t ws_size,
                              hipStream_t stream) {
    const float* x  = (const float*)d_in[0];
    const int*   E  = (const int*)d_in[1];
    const float* W1 = (const float*)d_in[2];
    const float* b1 = (const float*)d_in[3];
    const float* W2 = (const float*)d_in[4];
    const float* b2 = (const float*)d_in[5];
    const float* Wf = (const float*)d_in[6];
    const float* bf = (const float*)d_in[7];
    float* out = (float*)d_out;

    const int n  = in_sizes[0] / HID;   // 50000 nodes
    const int ne = in_sizes[1] / 2;     // 800000 edges
    const int nbuck  = (n + 31) / 32;   // 1563 buckets
    const int m      = nbuck * NBLK;    // 200,064 partition counters
    const int nbscan = (m + 255) / 256; // 782 scan blocks

    const size_t featB = (size_t)n * HID * 4;
    char* ws = (char*)d_ws;
    int*      flag = (int*)ws;
    ushort_t* wt1  = (ushort_t*)(ws + 1024);            // 32 KB
    ushort_t* wt2  = (ushort_t*)(ws + 1024 + 32768);    // 32 KB
    ushort_t* t1   = (ushort_t*)(ws + 1024 + 65536);    // n*128 bf16 (in featB slot)
    float*    h1   = (float*)(ws + 1024 + 65536 + featB);
    char*     p    = ws + 1024 + 65536 + 2 * featB;
    uint_t* pe    = (uint_t*)p;                 p += (size_t)ne * 4;
    int*   ovf    = (int*)p;                    p += (size_t)ne * 4;
    int*   histT  = (int*)p;                    p += (size_t)m * 4;
    int*   basea  = (int*)p;                    p += (size_t)(m + 1) * 4;
    int*   bsum   = (int*)p;                    p += (size_t)nbscan * 4;
    const size_t needed = (size_t)(p - ws);
    float* s = (float*)(ws + 1024 + 65536);   // t1 dead after aggregation; reuse slot

    const int gemm_grid = (n + 63) / 64;
    const bool csr_ok = (ws_size >= needed && n <= 65536 && nbuck <= MAXBUCK);

    // one launch: W transpose + is64 detect (+ dst histogram when CSR path)
    prep_hist<<<csr_ok ? (33 + NBLK) : 33, PTHREADS, 0, stream>>>(
        E, flag, W1, W2, wt1, wt2, histT, ne, n, nbuck);

    // layer 1 per-node transform (bf16 out) via MFMA
    mlp_mfma<<<gemm_grid, 256, 0, stream>>>(x, wt1, b1, nullptr, t1, nullptr, n, 0);

    if (csr_ok) {
        scang_blk<<<nbscan, 256, 0, stream>>>(histT, basea, bsum, m);
        scang_add2<<<nbscan, 256, 0, stream>>>(basea, bsum, nbscan, m);
        part_scatter<<<NBLK, PTHREADS, 0, stream>>>(E, flag, basea, pe, ne, n, nbuck);

        // fused bucket CSR + vector gather (writes H)
        bucket_gather<<<nbuck, 256, 0, stream>>>(pe, basea, t1, h1, ovf, n, nbuck);

        // layer 2 fused with readout: s[m] = relu(h1[m]@W2+b2) . Wf
        mlp_mfma<<<gemm_grid, 256, 0, stream>>>(h1, wt2, b2, Wf, nullptr, s, n, 1);

        // readout gather straight from pe
        bucket_scalar<<<nbuck, 256, 0, stream>>>(pe, basea, s, bf, out, n, nbuck);
    } else {
        // fallback: atomic scatter path
        (void)hipMemsetAsync(h1, 0, featB, stream);
        scatter_vec<<<8192, 256, 0, stream>>>(t1, E, flag, h1, ne, n);
        mlp_mfma<<<gemm_grid, 256, 0, stream>>>(h1, wt2, b2, Wf, nullptr, s, n, 1);
        init_out<<<(n + 255) / 256, 256, 0, stream>>>(out, bf, n);
        scatter_scalar<<<2048, 256, 0, stream>>>(s, E, flag, out, ne, n);
    }
}